// Round 1
// baseline (459.161 us; speedup 1.0000x reference)
//
#include <hip/hip_runtime.h>
#include <math.h>

// Problem constants
#define EPS 1e-8f
// inputs: [B=2, C=32, D=96, H=96, W=96] fp32, pooled to S=8 per axis (12^3 blocks)
// tokens L = 512, channels C = 32

// ---------------------------------------------------------------------------
// Kernel A: adaptive avg-pool 96^3 -> 8^3, write f[inp][b][l][c] (l = z*64+y*8+x)
// grid.x = 8192 = inp(2) * b(2) * c(32) * z(8) * y(8), 256 threads
// Each block covers 12 d-planes x 12 h-rows x 96 w = 13824 floats (54 KB).
// Thread layout: bucket = t&7 (the pooled x cell), u = t>>3 walks (d,h) pairs.
// Each lane reads 3 consecutive float4 (48 B) -> wave reads contiguous 3 KB.
// bucket is uniform per thread => single scalar accumulator (no scratch).
// ---------------------------------------------------------------------------
__global__ __launch_bounds__(256) void k_pool(const float* __restrict__ p1,
                                              const float* __restrict__ p2,
                                              float* __restrict__ fpool) {
    int gid = blockIdx.x;
    int y   = gid & 7;
    int z   = (gid >> 3) & 7;
    int c   = (gid >> 6) & 31;
    int b   = (gid >> 11) & 1;
    int inp = gid >> 12;
    const float* p = inp ? p2 : p1;
    const float4* p4 = reinterpret_cast<const float4*>(p);
    // base offset in float4 units (W=96 floats = 24 float4; plane = 9216 floats = 2304 f4)
    int base4 = ((b * 32 + c) * 96 + z * 12) * 2304 + y * 288;

    int t = threadIdx.x;
    int bucket = t & 7;   // pooled x index
    int u = t >> 3;       // [0,32): walks linear (d,h) index v

    float sum = 0.f;
    for (int v = u; v < 144; v += 32) {   // 144 = 12 d * 12 h
        int d = v / 12;
        int h = v - d * 12;
        int a4 = base4 + d * 2304 + h * 24 + bucket * 3;
        float4 x0 = p4[a4];
        float4 x1 = p4[a4 + 1];
        float4 x2 = p4[a4 + 2];
        sum += (x0.x + x0.y + x0.z + x0.w)
             + (x1.x + x1.y + x1.z + x1.w)
             + (x2.x + x2.y + x2.z + x2.w);
    }
    // reduce across lanes with same bucket (lanes differ in bits 3..5)
    sum += __shfl_xor(sum, 8);
    sum += __shfl_xor(sum, 16);
    sum += __shfl_xor(sum, 32);

    __shared__ float red[4][8];
    int wave = t >> 6;
    if ((t & 63) < 8) red[wave][t & 7] = sum;
    __syncthreads();
    if (t < 8) {
        float tot = red[0][t] + red[1][t] + red[2][t] + red[3][t];
        int l = z * 64 + y * 8 + t;
        fpool[(((inp * 2 + b) * 512 + l) << 5) + c] = tot * (1.f / 1728.f);
    }
}

// ---------------------------------------------------------------------------
// Kernel B: per-token L2 norms over 32 channels. 2048 tokens total.
// Also zeroes the scalar output (d_out is poisoned 0xAA before every launch).
// grid = 8 blocks x 256 threads.
// ---------------------------------------------------------------------------
__global__ __launch_bounds__(256) void k_norm(const float* __restrict__ fpool,
                                              float* __restrict__ nrm,
                                              float* __restrict__ out) {
    int idx = blockIdx.x * 256 + threadIdx.x;  // [0,2048)
    if (idx == 0) out[0] = 0.f;
    const float4* f4 = reinterpret_cast<const float4*>(fpool + idx * 32);
    float s = 0.f;
#pragma unroll
    for (int i = 0; i < 8; i++) {
        float4 v = f4[i];
        s += v.x * v.x + v.y * v.y + v.z * v.z + v.w * v.w;
    }
    nrm[idx] = sqrtf(s);
}

// ---------------------------------------------------------------------------
// Kernel C: pairwise cosine sims for both inputs + accumulate MSE.
// grid = (32 m-tiles, 32 l-tiles, 2 batches), 256 threads = 16x16 pairs.
// LDS tiles padded [16][33]: unpadded stride-32 gives a 16-way bank conflict
// on the column operand; +1 pad makes both operands conflict-free.
// ---------------------------------------------------------------------------
__global__ __launch_bounds__(256) void k_loss(const float* __restrict__ fpool,
                                              const float* __restrict__ nrm,
                                              float* __restrict__ out) {
    int b  = blockIdx.z;
    int lt = blockIdx.y * 16;
    int mt = blockIdx.x * 16;

    __shared__ float Al[16][33], Am[16][33], Bl[16][33], Bm[16][33];
    __shared__ float nAl[16], nAm[16], nBl[16], nBm[16];

    int t = threadIdx.x;
    int row = t >> 4;
    int c0 = (t & 15) << 1;  // two consecutive channels per thread
    const float2* f2 = reinterpret_cast<const float2*>(fpool);
    int h = c0 >> 1;
    int oAl = ((0 * 2 + b) * 512 + lt + row) * 16 + h;
    int oAm = ((0 * 2 + b) * 512 + mt + row) * 16 + h;
    int oBl = ((1 * 2 + b) * 512 + lt + row) * 16 + h;
    int oBm = ((1 * 2 + b) * 512 + mt + row) * 16 + h;
    float2 v;
    v = f2[oAl]; Al[row][c0] = v.x; Al[row][c0 + 1] = v.y;
    v = f2[oAm]; Am[row][c0] = v.x; Am[row][c0 + 1] = v.y;
    v = f2[oBl]; Bl[row][c0] = v.x; Bl[row][c0 + 1] = v.y;
    v = f2[oBm]; Bm[row][c0] = v.x; Bm[row][c0 + 1] = v.y;
    if (t < 16) {
        nAl[t] = nrm[(0 * 2 + b) * 512 + lt + t];
        nAm[t] = nrm[(0 * 2 + b) * 512 + mt + t];
        nBl[t] = nrm[(1 * 2 + b) * 512 + lt + t];
        nBm[t] = nrm[(1 * 2 + b) * 512 + mt + t];
    }
    __syncthreads();

    int tl = t >> 4, tm = t & 15;
    float da = 0.f, db = 0.f;
#pragma unroll
    for (int c = 0; c < 32; c++) {
        da += Al[tl][c] * Am[tm][c];
        db += Bl[tl][c] * Bm[tm][c];
    }
    float dena = fmaxf(nAl[tl] * nAm[tm], EPS);
    float denb = fmaxf(nBl[tl] * nBm[tm], EPS);
    float diff = da / dena - db / denb;
    float val = diff * diff * (1.f / (512.f * 512.f * 2.f));

    // block reduction -> one atomic per block
#pragma unroll
    for (int m = 1; m < 64; m <<= 1) val += __shfl_xor(val, m);
    __shared__ float red[4];
    if ((t & 63) == 0) red[t >> 6] = val;
    __syncthreads();
    if (t == 0) atomicAdd(out, red[0] + red[1] + red[2] + red[3]);
}

extern "C" void kernel_launch(void* const* d_in, const int* in_sizes, int n_in,
                              void* d_out, int out_size, void* d_ws, size_t ws_size,
                              hipStream_t stream) {
    const float* p1 = (const float*)d_in[0];
    const float* p2 = (const float*)d_in[1];
    float* out = (float*)d_out;

    // workspace layout: fpool [2][2][512][32] floats (256 KB), then nrm [2048] floats
    float* fpool = (float*)d_ws;
    float* nrm = fpool + 2 * 2 * 512 * 32;

    k_pool<<<8192, 256, 0, stream>>>(p1, p2, fpool);
    k_norm<<<8, 256, 0, stream>>>(fpool, nrm, out);
    k_loss<<<dim3(32, 32, 2), 256, 0, stream>>>(fpool, nrm, out);
}